// Round 1
// baseline (1158.461 us; speedup 1.0000x reference)
//
#include <hip/hip_runtime.h>

// KNN top-16: B=4, N=8192, D=16, k=16, fp32 in, int32 index out.
// FROZEN key model (validated R11-R18, absmax=0): harness np twin =
//   dot  = BLAS microkernel single-accumulator FMA chain, k = 0..15
//   norm = numpy AVX512 pairwise tree: r_j=m_j+m_{j+8}; q_j=r_j+r_{j+4};
//          fl(fl(q0+q2)+fl(q1+q3))
//   val  = fl( fl(ni + fl(-2*dot)) + nj ), ties -> lower index
// Keys packed u64 = (mono32(key)<<32)|idx: u64 asc == (key asc, idx asc).
// R20: occupancy experiment. Theory: latency-bound (3.2 waves/SIMD; 10
// dependent ds_reads feed FMAs every t-step; VALUBusy derived metric is
// gfx94x-fallback and likely overstates per-SIMD issue). LDS was 64KB
// (merge overlay) -> 2 blocks/CU. Now: two-pass merge (32KB overlay in
// pbuf region) + CAP 12->10 (pbuf 40KB). Total 48.5KB -> 3 blocks/CU,
// 24 waves/CU. Predict occupancy 40->~60%, dur -15-25% if latency-bound.

#define B_    4
#define N_    8192
#define D_    16
#define K_    16
#define SEGS_ 8
#define SEG_  (N_ / SEGS_)   // 1024
#define CH_   8              // rows per staged chunk
#define NCH_  (SEG_ / CH_)   // 128 chunks
#define BT_   512            // 8 waves
#define CAP_  10             // per-lane LDS push-buffer capacity
#define NQ_   (B_ * N_)      // 32768 queries

typedef unsigned long long u64;

// numpy AVX512 pairwise-sum tree for 16 contiguous floats. FROZEN.
__device__ __forceinline__ float np_norm16(const float* __restrict__ p) {
#pragma clang fp contract(off)
  float m[16];
#pragma unroll
  for (int d = 0; d < 16; ++d) m[d] = p[d] * p[d];
  float r[8];
#pragma unroll
  for (int j = 0; j < 8; ++j) r[j] = m[j] + m[j + 8];
  float q[4];
#pragma unroll
  for (int j = 0; j < 4; ++j) q[j] = r[j] + r[j + 4];
  return (q[0] + q[2]) + (q[1] + q[3]);
}

// monotone fp32->u32: uint ascending == float ascending (handles negatives)
__device__ __forceinline__ unsigned mono32(float f) {
  unsigned u = __float_as_uint(f);
  return u ^ ((unsigned)((int)u >> 31) | 0x80000000u);
}

__global__ __launch_bounds__(256) void knn_norms(const float* __restrict__ x,
                                                 float* __restrict__ nrm) {
  int q = blockIdx.x * 256 + threadIdx.x;
  float row[16];
  const float4* xv = (const float4*)(x + (size_t)q * D_);
  float4 a = xv[0], b = xv[1], c = xv[2], d = xv[3];
  row[0]=a.x; row[1]=a.y; row[2]=a.z; row[3]=a.w;
  row[4]=b.x; row[5]=b.y; row[6]=b.z; row[7]=b.w;
  row[8]=c.x; row[9]=c.y; row[10]=c.z; row[11]=c.w;
  row[12]=d.x; row[13]=d.y; row[14]=d.z; row[15]=d.w;
  nrm[q] = np_norm16(row);
}

// ascending insert; '>' keeps earlier (lower idx) on ties
__device__ __forceinline__ void insert16(float d, int j, float (&kd)[K_], int (&ki)[K_]) {
  float cd = d; int ci = j;
#pragma unroll
  for (int p = 0; p < K_; ++p) {
    bool gt = kd[p] > cd;
    float t0 = gt ? cd : kd[p];
    float t1 = gt ? kd[p] : cd;
    int   t2 = gt ? ci : ki[p];
    int   t3 = gt ? ki[p] : ci;
    kd[p] = t0; cd = t1; ki[p] = t2; ci = t3;
  }
}

__device__ __forceinline__ void flushbuf(u64* __restrict__ pbuf, int tid,
                                         int& count, float& thr,
                                         float (&kd)[K_], int (&ki)[K_]) {
#pragma unroll 1
  for (int s = 0; s < CAP_; ++s) {
    if (s < count) {
      u64 e = pbuf[(size_t)s * BT_ + tid];
      float d = __uint_as_float((unsigned)(e >> 32));
      if (d < thr) {
        int j = (int)(e & 0xffffu);
        insert16(d, j, kd, ki);
        thr = kd[K_ - 1];
      }
    }
  }
  count = 0;
}

__global__ __launch_bounds__(BT_, 6) void knn_fused(const float* __restrict__ x,
                                                    const float* __restrict__ nrm,
                                                    int* __restrict__ out) {
  __shared__ u64 smem[6208];                       // 48.5 KB -> 3 blocks/CU
  float4* stageR = (float4*)smem;                  // [(w*2+b)*32 + i], 8 KB
  float*  stageN = (float*)(smem + 1024);          // [(w*2+b)*8 + i], 512 B
  u64*    pbuf   = smem + 1088;                    // [s*512 + tid], 40 KB
  // merge overlay (after __syncthreads): smem+1088, (8*16*32)*8 = 32 KB

  const int tid  = threadIdx.x;
  const int w    = tid >> 6;                       // wave id = segment
  const int lane = tid & 63;                       // query-local id
  const int q    = blockIdx.x * 64 + lane;         // global query
  const int bq   = (int)((blockIdx.x * 64u) >> 13);  // batch (block-uniform)
  const int row0 = bq * N_ + w * SEG_;
  const float* __restrict__ cbase = x + (size_t)row0 * D_;
  const float* __restrict__ nbase = nrm + row0;

  float qa[D_];
  {
    const float4* qv = (const float4*)(x + (size_t)q * D_);
    float4 v0 = qv[0], v1 = qv[1], v2 = qv[2], v3 = qv[3];
    qa[0]=v0.x; qa[1]=v0.y; qa[2]=v0.z; qa[3]=v0.w;
    qa[4]=v1.x; qa[5]=v1.y; qa[6]=v1.z; qa[7]=v1.w;
    qa[8]=v2.x; qa[9]=v2.y; qa[10]=v2.z; qa[11]=v2.w;
    qa[12]=v3.x; qa[13]=v3.y; qa[14]=v3.z; qa[15]=v3.w;
  }
  const float ni = nrm[q];

  float kd[K_]; int ki[K_];
#pragma unroll
  for (int p = 0; p < K_; ++p) { kd[p] = 3.4e38f; ki[p] = 0; }
  float thr = 3.4e38f;
  int count = 0;

  // stage chunk 0 (per-wave-private LDS; wave-synchronous, no barrier)
  {
    const float4* gs = (const float4*)cbase;
    if (lane < 32) stageR[(w * 2 + 0) * 32 + lane] = gs[lane];
    if (lane < CH_) stageN[(w * 2 + 0) * CH_ + lane] = nbase[lane];
  }

#pragma unroll 1
  for (int c = 0; c < NCH_; ++c) {
    const int b = c & 1;
    // prefetch chunk c+1 into registers (overlaps compute below)
    float4 p0; float pn = 0.f;
    const bool more = (c + 1 < NCH_);
    if (more) {
      const float4* gs = (const float4*)(cbase + (size_t)(c + 1) * CH_ * D_);
      if (lane < 32) p0 = gs[lane];
      if (lane < CH_) pn = nbase[(c + 1) * CH_ + lane];
    }

    const float4* rows = stageR + (w * 2 + b) * 32;
    const float*  nn   = stageN + (w * 2 + b) * CH_;

#pragma unroll 1
    for (int t = 0; t < CH_; t += 2) {
      float4 r00 = rows[t*4+0], r01 = rows[t*4+1], r02 = rows[t*4+2], r03 = rows[t*4+3];
      float4 r10 = rows[t*4+4], r11 = rows[t*4+5], r12 = rows[t*4+6], r13 = rows[t*4+7];
      float nj0 = nn[t], nj1 = nn[t + 1];

      float c0[16] = {r00.x,r00.y,r00.z,r00.w, r01.x,r01.y,r01.z,r01.w,
                      r02.x,r02.y,r02.z,r02.w, r03.x,r03.y,r03.z,r03.w};
      float c1[16] = {r10.x,r10.y,r10.z,r10.w, r11.x,r11.y,r11.z,r11.w,
                      r12.x,r12.y,r12.z,r12.w, r13.x,r13.y,r13.z,r13.w};

      // two independent np-exact FMA chains (k ascending, single accumulator)
      float dot0 = 0.f, dot1 = 0.f;
#pragma unroll
      for (int d = 0; d < D_; ++d) {
        dot0 = __builtin_fmaf(qa[d], c0[d], dot0);
        dot1 = __builtin_fmaf(qa[d], c1[d], dot1);
      }
      float d0, d1;
      {
#pragma clang fp contract(off)
        float i0 = -2.0f * dot0;  float i1 = -2.0f * dot1;
        float u0 = ni + i0;       float u1 = ni + i1;
        d0 = u0 + nj0;            d1 = u1 + nj1;
      }

      if (d0 < thr) {
        pbuf[(size_t)count * BT_ + tid] =
            ((u64)__float_as_uint(d0) << 32) | (unsigned)(c * CH_ + t);
        ++count;
      }
      if (d1 < thr) {
        pbuf[(size_t)count * BT_ + tid] =
            ((u64)__float_as_uint(d1) << 32) | (unsigned)(c * CH_ + t + 1);
        ++count;
      }
      if (__any(count >= CAP_ - 1)) flushbuf(pbuf, tid, count, thr, kd, ki);
    }

    // write prefetched chunk into the other buffer
    if (more) {
      if (lane < 32) stageR[(w * 2 + (b ^ 1)) * 32 + lane] = p0;
      if (lane < CH_) stageN[(w * 2 + (b ^ 1)) * CH_ + lane] = pn;
    }
  }
  flushbuf(pbuf, tid, count, thr, kd, ki);

  // ---- publish sorted per-segment top-16 as packed u64, then 8-way merge ----
  // Two half-passes (queries [0,32) then [32,64)) so the overlay is 32 KB
  // and fits inside the pbuf region -> total LDS 48.5 KB -> 3 blocks/CU.
  u64* mrg = smem + 1088;                          // [(s*16+p)*32 + m], 32 KB
  const int half = lane >> 5;
  const int lm   = lane & 31;

  __syncthreads();   // all waves done with stage/push regions before overlay
#pragma unroll 1
  for (int h = 0; h < 2; ++h) {
    if (half == h) {
#pragma unroll
      for (int p = 0; p < K_; ++p) {
        mrg[((size_t)w * 16 + p) * 32 + lm] =
            ((u64)mono32(kd[p]) << 32) | (unsigned)(w * SEG_ + ki[p]);
      }
    }
    __syncthreads();

    // merge: 8 lanes per query; 32 queries -> tid<256 (waves 0..3).
    if (tid < 256) {
      const int m  = tid >> 3;                     // query-in-half
      const int s  = tid & 7;                      // my segment stream
      const int qi = h * 32 + m;                   // block-local query
      const int gq = blockIdx.x * 64 + qi;         // global query
      int ptr = 0;
#pragma unroll 1
      for (int r = 0; r < K_; ++r) {
        u64 hd = mrg[((size_t)s * 16 + ptr) * 32 + m];
        u64 mv = hd, o;
        o = __shfl_xor(mv, 1); mv = (o < mv) ? o : mv;
        o = __shfl_xor(mv, 2); mv = (o < mv) ? o : mv;
        o = __shfl_xor(mv, 4); mv = (o < mv) ? o : mv;
        if (hd == mv) ++ptr;                       // exactly one lane advances
        if (s == 0) out[(size_t)gq * K_ + r] = (int)(mv & 0xffffu);
      }
    }
    __syncthreads();                               // overlay reused by pass 2
  }
}

extern "C" void kernel_launch(void* const* d_in, const int* in_sizes, int n_in,
                              void* d_out, int out_size, void* d_ws, size_t ws_size,
                              hipStream_t stream) {
  const float* x = (const float*)d_in[0];
  float* nrm = (float*)d_ws;                       // 128 KB of workspace
  int* out = (int*)d_out;

  knn_norms<<<NQ_ / 256, 256, 0, stream>>>(x, nrm);
  knn_fused<<<NQ_ / 64, BT_, 0, stream>>>(x, nrm, out);
}

// Round 2
// 334.636 us; speedup vs baseline: 3.4619x; 3.4619x over previous
//
#include <hip/hip_runtime.h>

// KNN top-16: B=4, N=8192, D=16, k=16, fp32 in, int32 index out.
// FROZEN key model (validated R11-R18, absmax=0): harness np twin =
//   dot  = BLAS microkernel single-accumulator FMA chain, k = 0..15
//   norm = numpy AVX512 pairwise tree: r_j=m_j+m_{j+8}; q_j=r_j+r_{j+4};
//          fl(fl(q0+q2)+fl(q1+q3))
//   val  = fl( fl(ni + fl(-2*dot)) + nj ), ties -> lower index
// Keys packed u64 = (mono32(key)<<32)|idx: u64 asc == (key asc, idx asc).
// R21: occupancy experiment, take 2. R20 FAILED because launch_bounds
// (512,6) forced VGPR 56->40 -> qa/kd/ki spilled to scratch (WRITE_SIZE
// 2MB->195MB, dur 3.3x). Natural 56 VGPR already allows 8 waves/SIMD --
// registers never limited occupancy; only LDS does. Keep 48.5KB LDS
// (two-pass merge overlay 32KB + CAP 10 pbuf 40KB) -> 3 blocks/CU,
// restore launch_bounds(512,2). Predict: VGPR 56, WRITE_SIZE ~2MB,
// occupancy 40->~60%, dur -15-25% if latency-bound (else flat -> VALU).

#define B_    4
#define N_    8192
#define D_    16
#define K_    16
#define SEGS_ 8
#define SEG_  (N_ / SEGS_)   // 1024
#define CH_   8              // rows per staged chunk
#define NCH_  (SEG_ / CH_)   // 128 chunks
#define BT_   512            // 8 waves
#define CAP_  10             // per-lane LDS push-buffer capacity
#define NQ_   (B_ * N_)      // 32768 queries

typedef unsigned long long u64;

// numpy AVX512 pairwise-sum tree for 16 contiguous floats. FROZEN.
__device__ __forceinline__ float np_norm16(const float* __restrict__ p) {
#pragma clang fp contract(off)
  float m[16];
#pragma unroll
  for (int d = 0; d < 16; ++d) m[d] = p[d] * p[d];
  float r[8];
#pragma unroll
  for (int j = 0; j < 8; ++j) r[j] = m[j] + m[j + 8];
  float q[4];
#pragma unroll
  for (int j = 0; j < 4; ++j) q[j] = r[j] + r[j + 4];
  return (q[0] + q[2]) + (q[1] + q[3]);
}

// monotone fp32->u32: uint ascending == float ascending (handles negatives)
__device__ __forceinline__ unsigned mono32(float f) {
  unsigned u = __float_as_uint(f);
  return u ^ ((unsigned)((int)u >> 31) | 0x80000000u);
}

__global__ __launch_bounds__(256) void knn_norms(const float* __restrict__ x,
                                                 float* __restrict__ nrm) {
  int q = blockIdx.x * 256 + threadIdx.x;
  float row[16];
  const float4* xv = (const float4*)(x + (size_t)q * D_);
  float4 a = xv[0], b = xv[1], c = xv[2], d = xv[3];
  row[0]=a.x; row[1]=a.y; row[2]=a.z; row[3]=a.w;
  row[4]=b.x; row[5]=b.y; row[6]=b.z; row[7]=b.w;
  row[8]=c.x; row[9]=c.y; row[10]=c.z; row[11]=c.w;
  row[12]=d.x; row[13]=d.y; row[14]=d.z; row[15]=d.w;
  nrm[q] = np_norm16(row);
}

// ascending insert; '>' keeps earlier (lower idx) on ties
__device__ __forceinline__ void insert16(float d, int j, float (&kd)[K_], int (&ki)[K_]) {
  float cd = d; int ci = j;
#pragma unroll
  for (int p = 0; p < K_; ++p) {
    bool gt = kd[p] > cd;
    float t0 = gt ? cd : kd[p];
    float t1 = gt ? kd[p] : cd;
    int   t2 = gt ? ci : ki[p];
    int   t3 = gt ? ki[p] : ci;
    kd[p] = t0; cd = t1; ki[p] = t2; ci = t3;
  }
}

__device__ __forceinline__ void flushbuf(u64* __restrict__ pbuf, int tid,
                                         int& count, float& thr,
                                         float (&kd)[K_], int (&ki)[K_]) {
#pragma unroll 1
  for (int s = 0; s < CAP_; ++s) {
    if (s < count) {
      u64 e = pbuf[(size_t)s * BT_ + tid];
      float d = __uint_as_float((unsigned)(e >> 32));
      if (d < thr) {
        int j = (int)(e & 0xffffu);
        insert16(d, j, kd, ki);
        thr = kd[K_ - 1];
      }
    }
  }
  count = 0;
}

__global__ __launch_bounds__(BT_, 2) void knn_fused(const float* __restrict__ x,
                                                    const float* __restrict__ nrm,
                                                    int* __restrict__ out) {
  __shared__ u64 smem[6208];                       // 48.5 KB -> 3 blocks/CU
  float4* stageR = (float4*)smem;                  // [(w*2+b)*32 + i], 8 KB
  float*  stageN = (float*)(smem + 1024);          // [(w*2+b)*8 + i], 512 B
  u64*    pbuf   = smem + 1088;                    // [s*512 + tid], 40 KB
  // merge overlay (after __syncthreads): smem+1088, (8*16*32)*8 = 32 KB

  const int tid  = threadIdx.x;
  const int w    = tid >> 6;                       // wave id = segment
  const int lane = tid & 63;                       // query-local id
  const int q    = blockIdx.x * 64 + lane;         // global query
  const int bq   = (int)((blockIdx.x * 64u) >> 13);  // batch (block-uniform)
  const int row0 = bq * N_ + w * SEG_;
  const float* __restrict__ cbase = x + (size_t)row0 * D_;
  const float* __restrict__ nbase = nrm + row0;

  float qa[D_];
  {
    const float4* qv = (const float4*)(x + (size_t)q * D_);
    float4 v0 = qv[0], v1 = qv[1], v2 = qv[2], v3 = qv[3];
    qa[0]=v0.x; qa[1]=v0.y; qa[2]=v0.z; qa[3]=v0.w;
    qa[4]=v1.x; qa[5]=v1.y; qa[6]=v1.z; qa[7]=v1.w;
    qa[8]=v2.x; qa[9]=v2.y; qa[10]=v2.z; qa[11]=v2.w;
    qa[12]=v3.x; qa[13]=v3.y; qa[14]=v3.z; qa[15]=v3.w;
  }
  const float ni = nrm[q];

  float kd[K_]; int ki[K_];
#pragma unroll
  for (int p = 0; p < K_; ++p) { kd[p] = 3.4e38f; ki[p] = 0; }
  float thr = 3.4e38f;
  int count = 0;

  // stage chunk 0 (per-wave-private LDS; wave-synchronous, no barrier)
  {
    const float4* gs = (const float4*)cbase;
    if (lane < 32) stageR[(w * 2 + 0) * 32 + lane] = gs[lane];
    if (lane < CH_) stageN[(w * 2 + 0) * CH_ + lane] = nbase[lane];
  }

#pragma unroll 1
  for (int c = 0; c < NCH_; ++c) {
    const int b = c & 1;
    // prefetch chunk c+1 into registers (overlaps compute below)
    float4 p0; float pn = 0.f;
    const bool more = (c + 1 < NCH_);
    if (more) {
      const float4* gs = (const float4*)(cbase + (size_t)(c + 1) * CH_ * D_);
      if (lane < 32) p0 = gs[lane];
      if (lane < CH_) pn = nbase[(c + 1) * CH_ + lane];
    }

    const float4* rows = stageR + (w * 2 + b) * 32;
    const float*  nn   = stageN + (w * 2 + b) * CH_;

#pragma unroll 1
    for (int t = 0; t < CH_; t += 2) {
      float4 r00 = rows[t*4+0], r01 = rows[t*4+1], r02 = rows[t*4+2], r03 = rows[t*4+3];
      float4 r10 = rows[t*4+4], r11 = rows[t*4+5], r12 = rows[t*4+6], r13 = rows[t*4+7];
      float nj0 = nn[t], nj1 = nn[t + 1];

      float c0[16] = {r00.x,r00.y,r00.z,r00.w, r01.x,r01.y,r01.z,r01.w,
                      r02.x,r02.y,r02.z,r02.w, r03.x,r03.y,r03.z,r03.w};
      float c1[16] = {r10.x,r10.y,r10.z,r10.w, r11.x,r11.y,r11.z,r11.w,
                      r12.x,r12.y,r12.z,r12.w, r13.x,r13.y,r13.z,r13.w};

      // two independent np-exact FMA chains (k ascending, single accumulator)
      float dot0 = 0.f, dot1 = 0.f;
#pragma unroll
      for (int d = 0; d < D_; ++d) {
        dot0 = __builtin_fmaf(qa[d], c0[d], dot0);
        dot1 = __builtin_fmaf(qa[d], c1[d], dot1);
      }
      float d0, d1;
      {
#pragma clang fp contract(off)
        float i0 = -2.0f * dot0;  float i1 = -2.0f * dot1;
        float u0 = ni + i0;       float u1 = ni + i1;
        d0 = u0 + nj0;            d1 = u1 + nj1;
      }

      if (d0 < thr) {
        pbuf[(size_t)count * BT_ + tid] =
            ((u64)__float_as_uint(d0) << 32) | (unsigned)(c * CH_ + t);
        ++count;
      }
      if (d1 < thr) {
        pbuf[(size_t)count * BT_ + tid] =
            ((u64)__float_as_uint(d1) << 32) | (unsigned)(c * CH_ + t + 1);
        ++count;
      }
      if (__any(count >= CAP_ - 1)) flushbuf(pbuf, tid, count, thr, kd, ki);
    }

    // write prefetched chunk into the other buffer
    if (more) {
      if (lane < 32) stageR[(w * 2 + (b ^ 1)) * 32 + lane] = p0;
      if (lane < CH_) stageN[(w * 2 + (b ^ 1)) * CH_ + lane] = pn;
    }
  }
  flushbuf(pbuf, tid, count, thr, kd, ki);

  // ---- publish sorted per-segment top-16 as packed u64, then 8-way merge ----
  // Two half-passes (queries [0,32) then [32,64)) so the overlay is 32 KB
  // and fits inside the pbuf region -> total LDS 48.5 KB -> 3 blocks/CU.
  u64* mrg = smem + 1088;                          // [(s*16+p)*32 + m], 32 KB
  const int half = lane >> 5;
  const int lm   = lane & 31;

  __syncthreads();   // all waves done with stage/push regions before overlay
#pragma unroll 1
  for (int h = 0; h < 2; ++h) {
    if (half == h) {
#pragma unroll
      for (int p = 0; p < K_; ++p) {
        mrg[((size_t)w * 16 + p) * 32 + lm] =
            ((u64)mono32(kd[p]) << 32) | (unsigned)(w * SEG_ + ki[p]);
      }
    }
    __syncthreads();

    // merge: 8 lanes per query; 32 queries -> tid<256 (waves 0..3).
    if (tid < 256) {
      const int m  = tid >> 3;                     // query-in-half
      const int s  = tid & 7;                      // my segment stream
      const int qi = h * 32 + m;                   // block-local query
      const int gq = blockIdx.x * 64 + qi;         // global query
      int ptr = 0;
#pragma unroll 1
      for (int r = 0; r < K_; ++r) {
        u64 hd = mrg[((size_t)s * 16 + ptr) * 32 + m];
        u64 mv = hd, o;
        o = __shfl_xor(mv, 1); mv = (o < mv) ? o : mv;
        o = __shfl_xor(mv, 2); mv = (o < mv) ? o : mv;
        o = __shfl_xor(mv, 4); mv = (o < mv) ? o : mv;
        if (hd == mv) ++ptr;                       // exactly one lane advances
        if (s == 0) out[(size_t)gq * K_ + r] = (int)(mv & 0xffffu);
      }
    }
    __syncthreads();                               // overlay reused by pass 2
  }
}

extern "C" void kernel_launch(void* const* d_in, const int* in_sizes, int n_in,
                              void* d_out, int out_size, void* d_ws, size_t ws_size,
                              hipStream_t stream) {
  const float* x = (const float*)d_in[0];
  float* nrm = (float*)d_ws;                       // 128 KB of workspace
  int* out = (int*)d_out;

  knn_norms<<<NQ_ / 256, 256, 0, stream>>>(x, nrm);
  knn_fused<<<NQ_ / 64, BT_, 0, stream>>>(x, nrm, out);
}